// Round 13
// baseline (52.036 us; speedup 1.0000x reference)
//
#include <hip/hip_runtime.h>
#include <hip/hip_bf16.h>
#include <hip/hip_fp8.h>
#include <stdint.h>

typedef __attribute__((ext_vector_type(4))) float f32x4;
typedef __attribute__((ext_vector_type(16))) float f32x16;
typedef __attribute__((ext_vector_type(4))) unsigned int u32x4;
typedef __attribute__((ext_vector_type(8))) int i32x8;

#define N_ROWS 8192
#define DIM 256            // K (bytes per row in fp8)
#define BM 256             // i-rows per block (4 waves x 64 rows: t=2 of 32x32)
#define BJ 128             // j-cols staged per LDS tile
#define JCHUNKS 16
#define JCHUNK (N_ROWS / JCHUNKS)   // 512 -> 4 tiles of 128 per block

// r' = r_normalized * sqrt(10*log2(e)); dot(r'_i,r'_j) = 10*log2(e)*sim,
// so exp(10*sim) = exp2(dot).
#define SCL 3.79828252f

// E8M0 unit scale in all 4 bytes: 127 -> 2^0 = 1.0
#define UNIT_SCALE 0x7F7F7F7F

// ---- Kernel A: normalize rows -> fp8 e4m3 r'; zero den & out ---------------
__global__ void k_norm(const float* __restrict__ reps,
                       unsigned char* __restrict__ rq,
                       float* __restrict__ den,
                       float* __restrict__ out) {
  const int w = threadIdx.x >> 6, lane = threadIdx.x & 63;
  const int row = blockIdx.x * 4 + w;
  const float4 v = reinterpret_cast<const float4*>(reps + row * DIM)[lane];
  float ss = v.x * v.x + v.y * v.y + v.z * v.z + v.w * v.w;
#pragma unroll
  for (int m = 1; m < 64; m <<= 1) ss += __shfl_xor(ss, m);
  const float scale = SCL / fmaxf(sqrtf(ss), 1e-12f);
  // OCP e4m3 (gfx950 native); |r'| <= 3.8 << 448, no saturation concerns
  const uint32_t b0 = __hip_fp8_e4m3(v.x * scale).__x;
  const uint32_t b1 = __hip_fp8_e4m3(v.y * scale).__x;
  const uint32_t b2 = __hip_fp8_e4m3(v.z * scale).__x;
  const uint32_t b3 = __hip_fp8_e4m3(v.w * scale).__x;
  *reinterpret_cast<uint32_t*>(rq + (size_t)row * DIM + lane * 4) =
      b0 | (b1 << 8) | (b2 << 16) | (b3 << 24);
  if (threadIdx.x < 4) den[blockIdx.x * 4 + threadIdx.x] = 0.0f;
  if (blockIdx.x == 0 && threadIdx.x == 0) out[0] = 0.0f;
}

// ---- Kernel B: MX-fp8 32x32x64, 64 i-rows/wave, fused sim+exp+mask+sum -----
// grid (32,16), 256 thr (4 waves), 64KB LDS dbuf -> 2 blocks/CU.
// 32x32x64 mfma_scale lets one wave own 64 i-rows with only 64 A-VGPRs
// (t=4 @16x16 needed the same rows at ~160 arch -> spilled, R11). LDS-read
// total = N^2*DIM/rows_per_wave -> halves vs R10 (10.2 -> 5.1us floor);
// MFMA (7.3us) becomes the binding pipe. No launch_bounds: let the
// allocator exceed 128 arch (m97-style); LDS caps occupancy at 2 blocks/CU.
__global__ __attribute__((amdgpu_flat_work_group_size(256, 256))) void k_sim(
    const unsigned char* __restrict__ rq,
    const int* __restrict__ lab,
    float* __restrict__ den) {
  __shared__ unsigned char Bs[2][BJ * DIM];  // 2 x 32 KB, 16B-chunk XOR-swizzled

  const int tid = threadIdx.x;
  const int w = tid >> 6, lane = tid & 63;
  const int l15 = lane & 15, lq = lane >> 4;
  const int l31 = lane & 31, lh = lane >> 5;
  const int ibase = blockIdx.x * BM + w * 64;   // this wave's 64 rows
  const int jc0 = blockIdx.y * JCHUNK;

  // A fragments: 2 i-subtiles (32 rows) x 4 K-windows (32B each) = 64 VGPR.
  // 32x32x64 operand map (lane l: row l&31, K-half l>>5); same map for A and
  // B from the same matrix so any within-half K-permutation cancels.
  i32x8 a[2][4];
#pragma unroll
  for (int t = 0; t < 2; ++t) {
    const unsigned char* ap = rq + (size_t)(ibase + t * 32 + l31) * DIM + lh * 32;
#pragma unroll
    for (int kc = 0; kc < 4; ++kc) {
      const u32x4 v0 = *reinterpret_cast<const u32x4*>(ap + kc * 64);
      const u32x4 v1 = *reinterpret_cast<const u32x4*>(ap + kc * 64 + 16);
      a[t][kc] = (i32x8){(int)v0.x, (int)v0.y, (int)v0.z, (int)v0.w,
                         (int)v1.x, (int)v1.y, (int)v1.z, (int)v1.w};
    }
  }

  // labels for this lane's output rows, byte-packed (labels are 0..99):
  // C/D row = (r&3) + 8*(r>>2) + 4*lh (+ t*32); byte (r&3) of labi_pk[t][r>>2]
  uint32_t labi_pk[2][4];
#pragma unroll
  for (int t = 0; t < 2; ++t)
#pragma unroll
    for (int g = 0; g < 4; ++g) {
      const int base = ibase + t * 32 + 8 * g + 4 * lh;
      labi_pk[t][g] = (uint32_t)(lab[base] & 0xFF) |
                      ((uint32_t)(lab[base + 1] & 0xFF) << 8) |
                      ((uint32_t)(lab[base + 2] & 0xFF) << 16) |
                      ((uint32_t)(lab[base + 3] & 0xFF) << 24);
    }

  f32x16 dsum[2];
#pragma unroll
  for (int t = 0; t < 2; ++t)
#pragma unroll
    for (int r = 0; r < 16; ++r) dsum[t][r] = 0.0f;

  const int lrow0 = w * 32;  // each wave stages 32 rows (8 instr x 4 rows)

  // prologue: stage tile 0 into buf 0
#pragma unroll
  for (int q = 0; q < 8; ++q) {
    const int lrow = lrow0 + q * 4 + lq;
    const int ch = l15 ^ (lrow & 7);  // 16B-chunk swizzle
    const unsigned char* g = rq + (size_t)(jc0 + lrow) * DIM + ch * 16;
    unsigned char* l = Bs[0] + (lrow0 + q * 4) * DIM;  // +lane*16 implicit
    __builtin_amdgcn_global_load_lds(
        (const __attribute__((address_space(1))) uint32_t*)g,
        (__attribute__((address_space(3))) uint32_t*)l, 16, 0, 0);
  }

  for (int jt = 0; jt < JCHUNK / BJ; ++jt) {
    const int cur = jt & 1;
    const int j0 = jc0 + jt * BJ;

    __syncthreads();  // buf[cur] staged; prior reads of buf[cur^1] done

    // issue staging of NEXT tile into the other buffer (hidden under compute)
    if (jt < JCHUNK / BJ - 1) {
      const int jn = j0 + BJ;
#pragma unroll
      for (int q = 0; q < 8; ++q) {
        const int lrow = lrow0 + q * 4 + lq;
        const int ch = l15 ^ (lrow & 7);
        const unsigned char* g = rq + (size_t)(jn + lrow) * DIM + ch * 16;
        unsigned char* l = Bs[cur ^ 1] + (lrow0 + q * 4) * DIM;
        __builtin_amdgcn_global_load_lds(
            (const __attribute__((address_space(1))) uint32_t*)g,
            (__attribute__((address_space(3))) uint32_t*)l, 16, 0, 0);
      }
    }

    // j-labels for this lane's column (col = l31), byte s of labj_pk
    const uint32_t labj_pk =
        (uint32_t)(lab[j0 + l31] & 0xFF) |
        ((uint32_t)(lab[j0 + 32 + l31] & 0xFF) << 8) |
        ((uint32_t)(lab[j0 + 64 + l31] & 0xFF) << 16) |
        ((uint32_t)(lab[j0 + 96 + l31] & 0xFF) << 24);

    const unsigned char* Bb = Bs[cur];
#pragma unroll
    for (int s = 0; s < 4; ++s) {
      f32x16 acc0, acc1;
#pragma unroll
      for (int r = 0; r < 16; ++r) { acc0[r] = 0.0f; acc1[r] = 0.0f; }
      const int brow = s * 32 + l31;
      const unsigned char* bp = Bb + brow * DIM;
      const int sw = brow & 7;
#pragma unroll
      for (int kc = 0; kc < 4; ++kc) {
        const int c0 = kc * 4 + lh * 2;
        const u32x4 b0 = *reinterpret_cast<const u32x4*>(bp + (c0 ^ sw) * 16);
        const u32x4 b1 = *reinterpret_cast<const u32x4*>(bp + ((c0 + 1) ^ sw) * 16);
        const i32x8 bb = (i32x8){(int)b0.x, (int)b0.y, (int)b0.z, (int)b0.w,
                                 (int)b1.x, (int)b1.y, (int)b1.z, (int)b1.w};
        acc0 = __builtin_amdgcn_mfma_scale_f32_32x32x64_f8f6f4(
            a[0][kc], bb, acc0, 0, 0, 0, UNIT_SCALE, 0, UNIT_SCALE);
        acc1 = __builtin_amdgcn_mfma_scale_f32_32x32x64_f8f6f4(
            a[1][kc], bb, acc1, 0, 0, 0, UNIT_SCALE, 0, UNIT_SCALE);
      }
      const int lj = (int)((labj_pk >> (s * 8)) & 0xFF);
#pragma unroll
      for (int r = 0; r < 16; ++r) {
        const float e0 = __builtin_amdgcn_exp2f(acc0[r]);
        const float e1 = __builtin_amdgcn_exp2f(acc1[r]);
        const int li0 = (int)((labi_pk[0][r >> 2] >> ((r & 3) * 8)) & 0xFF);
        const int li1 = (int)((labi_pk[1][r >> 2] >> ((r & 3) * 8)) & 0xFF);
        dsum[0][r] += (li0 == lj) ? 1.0f : e0;
        dsum[1][r] += (li1 == lj) ? 1.0f : e1;
      }
    }
  }

  // row-sum: reduce over the 32 lanes (same half) sharing each output row
#pragma unroll
  for (int t = 0; t < 2; ++t)
#pragma unroll
    for (int r = 0; r < 16; ++r) {
      float v = dsum[t][r];
      v += __shfl_xor(v, 1);
      v += __shfl_xor(v, 2);
      v += __shfl_xor(v, 4);
      v += __shfl_xor(v, 8);
      v += __shfl_xor(v, 16);
      if (l31 == 0)
        atomicAdd(&den[ibase + t * 32 + (r & 3) + 8 * (r >> 2) + 4 * lh], v);
    }
}

// ---- Kernel C: loss = mean(log(den + 1 + eps)) -----------------------------
__global__ void k_loss(const float* __restrict__ den, float* __restrict__ out) {
  const int idx = blockIdx.x * 256 + threadIdx.x;
  float v = logf(den[idx] + 1.0f + 1e-8f);  // +1 = num_diag
#pragma unroll
  for (int m = 1; m < 64; m <<= 1) v += __shfl_xor(v, m);
  __shared__ float sred[4];
  if ((threadIdx.x & 63) == 0) sred[threadIdx.x >> 6] = v;
  __syncthreads();
  if (threadIdx.x == 0)
    atomicAdd(out, (sred[0] + sred[1] + sred[2] + sred[3]) * (1.0f / (float)N_ROWS));
}

extern "C" void kernel_launch(void* const* d_in, const int* in_sizes, int n_in,
                              void* d_out, int out_size, void* d_ws, size_t ws_size,
                              hipStream_t stream) {
  const float* reps = (const float*)d_in[0];
  const int* lab = (const int*)d_in[1];
  float* out = (float*)d_out;
  unsigned char* rq = (unsigned char*)d_ws;                        // 2 MB fp8 r'
  float* den = (float*)((char*)d_ws + (size_t)N_ROWS * DIM);       // 32 KB

  k_norm<<<N_ROWS / 4, 256, 0, stream>>>(reps, rq, den, out);
  k_sim<<<dim3(N_ROWS / BM, JCHUNKS), 256, 0, stream>>>(rq, lab, den);
  k_loss<<<N_ROWS / 256, 256, 0, stream>>>(den, out);
}

// Round 14
// 52.011 us; speedup vs baseline: 1.0005x; 1.0005x over previous
//
#include <hip/hip_runtime.h>
#include <hip/hip_bf16.h>
#include <hip/hip_fp8.h>
#include <stdint.h>

typedef __attribute__((ext_vector_type(4))) float f32x4;
typedef __attribute__((ext_vector_type(2))) unsigned int u32x2;
typedef __attribute__((ext_vector_type(4))) unsigned int u32x4;
typedef __attribute__((ext_vector_type(8))) int i32x8;

#define N_ROWS 8192
#define DIM 256            // K (bytes per row in fp8)
#define BJ 128             // j-cols per LDS tile
#define NTILE 64           // 8192 / 128

// r' = r_normalized * sqrt(10*log2(e)); dot(r'_i,r'_j) = 10*log2(e)*sim,
// so exp(10*sim) = exp2(dot).
#define SCL 3.79828252f
// E8M0 unit scale in all 4 bytes: 127 -> 2^0 = 1.0
#define UNIT_SCALE 0x7F7F7F7F

// ---- Kernel A: normalize rows -> fp8 e4m3 r'; zero den, part, out ----------
__global__ void k_norm(const float* __restrict__ reps,
                       unsigned char* __restrict__ rq,
                       float* __restrict__ den,
                       float* __restrict__ part,
                       float* __restrict__ out) {
  const int w = threadIdx.x >> 6, lane = threadIdx.x & 63;
  const int row = blockIdx.x * 4 + w;
  const float4 v = reinterpret_cast<const float4*>(reps + row * DIM)[lane];
  float ss = v.x * v.x + v.y * v.y + v.z * v.z + v.w * v.w;
#pragma unroll
  for (int m = 1; m < 64; m <<= 1) ss += __shfl_xor(ss, m);
  const float scale = SCL / fmaxf(sqrtf(ss), 1e-12f);
  const uint32_t b0 = __hip_fp8_e4m3(v.x * scale).__x;
  const uint32_t b1 = __hip_fp8_e4m3(v.y * scale).__x;
  const uint32_t b2 = __hip_fp8_e4m3(v.z * scale).__x;
  const uint32_t b3 = __hip_fp8_e4m3(v.w * scale).__x;
  *reinterpret_cast<uint32_t*>(rq + (size_t)row * DIM + lane * 4) =
      b0 | (b1 << 8) | (b2 << 16) | (b3 << 24);
  // zero part: 2048 blocks x 256 threads = 524288 = 64*8192 cells
  part[blockIdx.x * 256 + threadIdx.x] = 0.0f;
  if (threadIdx.x < 4) den[blockIdx.x * 4 + threadIdx.x] = 0.0f;
  if (blockIdx.x == 0 && threadIdx.x == 0) out[0] = 0.0f;
}

// ---- Kernel B: triangular MX-fp8 fused sim + exp + mask + row/col sums -----
// Balanced pairing: pair p covers tile-rows {p, 63-p} = 65 tiles, split into
// 16 chunks -> 512 blocks (2/CU), 256 thr (4 waves x 32 i-rows, t=2).
// R10's staging (prefetch next tile into other 32KB buffer, ONE barrier per
// tile) and 16x16x128 MX-fp8 inner loop, verbatim. Off-diagonal tiles emit
// row-sums (registers -> rare atomics) AND col-sums (in-lane + shfl reduce ->
// double-buffered LDS colacc -> one plain store per tile into an exclusive
// cell of part[64][8192]; m_ij == m_ji bit-exactly since A/B use the same
// k-map from the same matrix).
__global__ __launch_bounds__(256, 2) void k_simt(
    const unsigned char* __restrict__ rq,
    const int* __restrict__ lab,
    float* __restrict__ den,
    float* __restrict__ part) {
  __shared__ unsigned char Bs[2][BJ * DIM];  // 2 x 32 KB, 16B-chunk XOR-swizzled
  __shared__ float colacc[2][4][128];        // double-buffered col partials

  const int p = blockIdx.x >> 4;   // pair 0..31
  const int q = blockIdx.x & 15;   // chunk 0..15
  const int c0 = q * 4 + (q > 0 ? 1 : 0);
  const int nc = (q == 0) ? 5 : 4;

  const int tid = threadIdx.x;
  const int w = tid >> 6, lane = tid & 63;
  const int l15 = lane & 15, lq = lane >> 4;
  const int lrow0 = w * 32;  // each wave stages 32 rows (8 instr x 4 rows)

  // prologue: stage first tile's B into buf 0
  {
    int cc = c0;
    const int tj = (cc <= p) ? cc : (cc - p - 1);
#pragma unroll
    for (int qq = 0; qq < 8; ++qq) {
      const int lrow = lrow0 + qq * 4 + lq;
      const int ch = l15 ^ (lrow & 7);  // 16B-chunk swizzle
      const unsigned char* g = rq + (size_t)(tj * 128 + lrow) * DIM + ch * 16;
      unsigned char* l = Bs[0] + (lrow0 + qq * 4) * DIM;  // +lane*16 implicit
      __builtin_amdgcn_global_load_lds(
          (const __attribute__((address_space(1))) uint32_t*)g,
          (__attribute__((address_space(3))) uint32_t*)l, 16, 0, 0);
    }
  }

  i32x8 a[2][2];
  int labi[2][4];
  f32x4 dsum[2] = {{0.f, 0.f, 0.f, 0.f}, {0.f, 0.f, 0.f, 0.f}};
  int cur_ti = -1, cur_ibase = 0;
  int prev_store = 0, prev_ti = 0, prev_tj = 0;

  for (int idx = 0; idx < nc; ++idx) {
    const int cc = c0 + idx;
    const int cur = idx & 1;
    int ti, tj;
    if (cc <= p) { ti = p; tj = cc; }
    else         { ti = 63 - p; tj = cc - p - 1; }
    const int jbase = tj * 128;

    __syncthreads();  // buf[cur] staged; prior reads of buf[cur^1] done

    // issue staging of NEXT tile into the other buffer (hidden under compute)
    if (idx + 1 < nc) {
      const int ccn = cc + 1;
      const int tjn = (ccn <= p) ? ccn : (ccn - p - 1);
#pragma unroll
      for (int qq = 0; qq < 8; ++qq) {
        const int lrow = lrow0 + qq * 4 + lq;
        const int ch = l15 ^ (lrow & 7);
        const unsigned char* g = rq + (size_t)(tjn * 128 + lrow) * DIM + ch * 16;
        unsigned char* l = Bs[cur ^ 1] + (lrow0 + qq * 4) * DIM;
        __builtin_amdgcn_global_load_lds(
            (const __attribute__((address_space(1))) uint32_t*)g,
            (__attribute__((address_space(3))) uint32_t*)l, 16, 0, 0);
      }
    }

    // previous tile's col partials -> part (exclusive cell, plain store)
    if (prev_store && tid < 128)
      part[(size_t)prev_ti * N_ROWS + prev_tj * 128 + tid] =
          colacc[cur ^ 1][0][tid] + colacc[cur ^ 1][1][tid] +
          colacc[cur ^ 1][2][tid] + colacc[cur ^ 1][3][tid];

    // i-row-group switch: flush row sums, load new A fragments + labels
    if (ti != cur_ti) {
      if (cur_ti >= 0) {
#pragma unroll
        for (int t = 0; t < 2; ++t)
#pragma unroll
          for (int r = 0; r < 4; ++r) {
            float v = dsum[t][r];
            v += __shfl_xor(v, 1);
            v += __shfl_xor(v, 2);
            v += __shfl_xor(v, 4);
            v += __shfl_xor(v, 8);
            if (l15 == 0) atomicAdd(&den[cur_ibase + t * 16 + lq * 4 + r], v);
            dsum[t][r] = 0.f;
          }
      }
      cur_ti = ti;
      cur_ibase = ti * 128 + w * 32;
#pragma unroll
      for (int t = 0; t < 2; ++t) {
        const unsigned char* ap =
            rq + (size_t)(cur_ibase + t * 16 + l15) * DIM + lq * 32;
#pragma unroll
        for (int kc = 0; kc < 2; ++kc) {
          const u32x4 v0 = *reinterpret_cast<const u32x4*>(ap + kc * 128);
          const u32x4 v1 = *reinterpret_cast<const u32x4*>(ap + kc * 128 + 16);
          a[t][kc] = (i32x8){(int)v0.x, (int)v0.y, (int)v0.z, (int)v0.w,
                             (int)v1.x, (int)v1.y, (int)v1.z, (int)v1.w};
        }
      }
#pragma unroll
      for (int t = 0; t < 2; ++t)
#pragma unroll
        for (int r = 0; r < 4; ++r)
          labi[t][r] = lab[cur_ibase + t * 16 + lq * 4 + r];
    }

    int labj[8];
#pragma unroll
    for (int s = 0; s < 8; ++s) labj[s] = lab[jbase + s * 16 + l15];

    const bool offd = (ti != tj);
    const unsigned char* Bb = Bs[cur];
#pragma unroll
    for (int s = 0; s < 8; ++s) {
      f32x4 acc0 = {0.f, 0.f, 0.f, 0.f};
      f32x4 acc1 = {0.f, 0.f, 0.f, 0.f};
      const int brow = s * 16 + l15;
      const unsigned char* bp = Bb + brow * DIM;
      const int sw = brow & 7;
#pragma unroll
      for (int kc = 0; kc < 2; ++kc) {
        const int base = kc * 8 + lq * 2;
        const u32x4 b0 = *reinterpret_cast<const u32x4*>(bp + (base ^ sw) * 16);
        const u32x4 b1 = *reinterpret_cast<const u32x4*>(bp + ((base + 1) ^ sw) * 16);
        const i32x8 bb = (i32x8){(int)b0.x, (int)b0.y, (int)b0.z, (int)b0.w,
                                 (int)b1.x, (int)b1.y, (int)b1.z, (int)b1.w};
        acc0 = __builtin_amdgcn_mfma_scale_f32_16x16x128_f8f6f4(
            a[0][kc], bb, acc0, 0, 0, 0, UNIT_SCALE, 0, UNIT_SCALE);
        acc1 = __builtin_amdgcn_mfma_scale_f32_16x16x128_f8f6f4(
            a[1][kc], bb, acc1, 0, 0, 0, UNIT_SCALE, 0, UNIT_SCALE);
      }
      float colp = 0.f;
#pragma unroll
      for (int r = 0; r < 4; ++r) {
        const float e0 = __builtin_amdgcn_exp2f(acc0[r]);
        const float e1 = __builtin_amdgcn_exp2f(acc1[r]);
        const float m0 = (labi[0][r] == labj[s]) ? 1.0f : e0;
        const float m1 = (labi[1][r] == labj[s]) ? 1.0f : e1;
        dsum[0][r] += m0;
        dsum[1][r] += m1;
        colp += m0 + m1;
      }
      if (offd) {
        colp += __shfl_xor(colp, 16);
        colp += __shfl_xor(colp, 32);
        if (lane < 16) colacc[cur][w][s * 16 + l15] = colp;
      }
    }
    prev_store = offd ? 1 : 0;
    prev_ti = ti;
    prev_tj = tj;
  }

  // drain: last tile's col partials + final row-sum flush
  __syncthreads();
  if (prev_store && tid < 128) {
    const int lastbuf = (nc - 1) & 1;
    part[(size_t)prev_ti * N_ROWS + prev_tj * 128 + tid] =
        colacc[lastbuf][0][tid] + colacc[lastbuf][1][tid] +
        colacc[lastbuf][2][tid] + colacc[lastbuf][3][tid];
  }
#pragma unroll
  for (int t = 0; t < 2; ++t)
#pragma unroll
    for (int r = 0; r < 4; ++r) {
      float v = dsum[t][r];
      v += __shfl_xor(v, 1);
      v += __shfl_xor(v, 2);
      v += __shfl_xor(v, 4);
      v += __shfl_xor(v, 8);
      if (l15 == 0) atomicAdd(&den[cur_ibase + t * 16 + lq * 4 + r], v);
    }
}

// ---- Kernel C: loss = mean(log(den + colparts + 1 + eps)) ------------------
__global__ void k_loss(const float* __restrict__ den,
                       const float* __restrict__ part,
                       float* __restrict__ out) {
  const int idx = blockIdx.x * 256 + threadIdx.x;
  float v = den[idx] + 1.0f + 1e-8f;  // +1 = num_diag
#pragma unroll
  for (int a2 = 0; a2 < NTILE; ++a2) v += part[(size_t)a2 * N_ROWS + idx];
  v = logf(v);
#pragma unroll
  for (int m = 1; m < 64; m <<= 1) v += __shfl_xor(v, m);
  __shared__ float sred[4];
  if ((threadIdx.x & 63) == 0) sred[threadIdx.x >> 6] = v;
  __syncthreads();
  if (threadIdx.x == 0)
    atomicAdd(out, (sred[0] + sred[1] + sred[2] + sred[3]) * (1.0f / (float)N_ROWS));
}

extern "C" void kernel_launch(void* const* d_in, const int* in_sizes, int n_in,
                              void* d_out, int out_size, void* d_ws, size_t ws_size,
                              hipStream_t stream) {
  const float* reps = (const float*)d_in[0];
  const int* lab = (const int*)d_in[1];
  float* out = (float*)d_out;
  unsigned char* rq = (unsigned char*)d_ws;                        // 2 MB fp8 r'
  float* den = (float*)((char*)d_ws + (size_t)N_ROWS * DIM);       // 32 KB
  float* part = (float*)((char*)d_ws + (size_t)N_ROWS * DIM
                         + (size_t)N_ROWS * 4);                    // 2 MB

  k_norm<<<N_ROWS / 4, 256, 0, stream>>>(reps, rq, den, part, out);
  k_simt<<<512, 256, 0, stream>>>(rq, lab, den, part);
  k_loss<<<N_ROWS / 256, 256, 0, stream>>>(den, part, out);
}

// Round 15
// 30.278 us; speedup vs baseline: 1.7186x; 1.7178x over previous
//
#include <hip/hip_runtime.h>
#include <hip/hip_bf16.h>
#include <stdint.h>

typedef __attribute__((ext_vector_type(4))) float f32x4;
typedef __attribute__((ext_vector_type(4))) unsigned int u32x4;
typedef __attribute__((ext_vector_type(8))) int i32x8;

#define N_ROWS 8192
#define DIM 256            // K elements per row
#define ROWB 128           // bytes per row in fp4 (2 elems/byte)
#define BM 128             // i-rows per block (4 waves x 32 rows, t=2)
#define BJ 128             // j-cols staged per LDS tile
#define JCHUNKS 8
#define JCHUNK (N_ROWS / JCHUNKS)   // 1024 -> 8 tiles of 128 per block

// r' = r_normalized * sqrt(10*log2(e)); dot(r'_i,r'_j) = 10*log2(e)*sim,
// so exp(10*sim) = exp2(dot).
#define SCL 3.79828252f

// E8M0 scale 2^-3 in all 4 bytes (127-3=124): data quantized as q=8*r',
// scale applied to BOTH A and B -> products x 2^-6 = exact /64.
#define SCALE_M3 0x7C7C7C7C

// e2m1 RTNE quantizer: grid {0,.5,1,1.5,2,3,4,6} x sign
__device__ __forceinline__ uint32_t q_e2m1(float y) {
  const uint32_t s = (__builtin_bit_cast(uint32_t, y) >> 31) << 3;
  const float a = fabsf(y);
  const uint32_t c = (a < 0.25f) ? 0u : (a < 0.75f) ? 1u : (a < 1.25f) ? 2u
                   : (a < 1.75f) ? 3u : (a < 2.5f)  ? 4u : (a < 3.5f)  ? 5u
                   : (a < 5.0f)  ? 6u : 7u;
  return s | c;
}

// ---- Kernel A: normalize rows -> fp4 e2m1 q=8*r'; zero den & out -----------
__global__ void k_norm(const float* __restrict__ reps,
                       unsigned char* __restrict__ rq,
                       float* __restrict__ den,
                       float* __restrict__ out) {
  const int w = threadIdx.x >> 6, lane = threadIdx.x & 63;
  const int row = blockIdx.x * 4 + w;
  const float4 v = reinterpret_cast<const float4*>(reps + row * DIM)[lane];
  float ss = v.x * v.x + v.y * v.y + v.z * v.z + v.w * v.w;
#pragma unroll
  for (int m = 1; m < 64; m <<= 1) ss += __shfl_xor(ss, m);
  const float qs = 8.0f * SCL / fmaxf(sqrtf(ss), 1e-12f);
  const uint32_t nib = q_e2m1(v.x * qs) | (q_e2m1(v.y * qs) << 4) |
                       (q_e2m1(v.z * qs) << 8) | (q_e2m1(v.w * qs) << 12);
  *reinterpret_cast<unsigned short*>(rq + (size_t)row * ROWB + lane * 2) =
      (unsigned short)nib;
  if (threadIdx.x < 4) den[blockIdx.x * 4 + threadIdx.x] = 0.0f;
  if (blockIdx.x == 0 && threadIdx.x == 0) out[0] = 0.0f;
}

// ---- Kernel B: MX-fp4 (16x16x128) fused sim + exp + mask + row-sum ---------
// R10's exact structure (grid (64,8), 256 thr, dbuf LDS, 1 barrier/tile,
// prefetch into other buffer); only dtype changes. LDS tile 16 KB (2 -> 32KB
// total), 16 ds_read_b128/wave/tile (half of fp8), fp4 MFMA at ~1.55x fp8
// rate. Register demand ~80 << 128 cap of launch_bounds(256,2).
__global__ __launch_bounds__(256, 2) void k_sim(
    const unsigned char* __restrict__ rq,
    const int* __restrict__ lab,
    float* __restrict__ den) {
  __shared__ unsigned char Bs[2][BJ * ROWB];  // 2 x 16 KB, 16B-chunk XOR-swizzled

  const int tid = threadIdx.x;
  const int w = tid >> 6, lane = tid & 63;
  const int l15 = lane & 15, lq = lane >> 4;
  const int ibase = blockIdx.x * BM + w * 32;   // this wave's 32 rows
  const int jc0 = blockIdx.y * JCHUNK;

  // A fragments: 2 i-subtiles x 2 K-windows; fp4 uses 16B/lane (4 VGPR) in
  // regs 0-3 of the v8i32 operand. Window kc = row bytes [kc*64+lq*16,+16).
  // Same map for A and B from the same matrix -> any k-permutation cancels.
  i32x8 a[2][2];
#pragma unroll
  for (int t = 0; t < 2; ++t) {
    const unsigned char* ap = rq + (size_t)(ibase + t * 16 + l15) * ROWB;
#pragma unroll
    for (int kc = 0; kc < 2; ++kc) {
      const u32x4 v0 = *reinterpret_cast<const u32x4*>(ap + kc * 64 + lq * 16);
      a[t][kc] = (i32x8){(int)v0.x, (int)v0.y, (int)v0.z, (int)v0.w, 0, 0, 0, 0};
    }
  }
  int labi[2][4];
#pragma unroll
  for (int t = 0; t < 2; ++t)
#pragma unroll
    for (int r = 0; r < 4; ++r)
      labi[t][r] = lab[ibase + t * 16 + lq * 4 + r];

  f32x4 dsum[2] = {{0.f, 0.f, 0.f, 0.f}, {0.f, 0.f, 0.f, 0.f}};

  const int lrow0 = w * 32;  // each wave stages 32 rows (4 instr x 8 rows)

  // prologue: stage tile 0 into buf 0 (16 KB: 4 instr x 4 waves x 1 KB)
#pragma unroll
  for (int q = 0; q < 4; ++q) {
    const int lrow = lrow0 + q * 8 + (lane >> 3);
    const int ch = (lane & 7) ^ (lrow & 7);  // 16B-chunk swizzle (8 chunks/row)
    const unsigned char* g = rq + (size_t)(jc0 + lrow) * ROWB + ch * 16;
    unsigned char* l = Bs[0] + (lrow0 + q * 8) * ROWB;  // +lane*16 implicit
    __builtin_amdgcn_global_load_lds(
        (const __attribute__((address_space(1))) uint32_t*)g,
        (__attribute__((address_space(3))) uint32_t*)l, 16, 0, 0);
  }

  for (int jt = 0; jt < JCHUNK / BJ; ++jt) {
    const int cur = jt & 1;
    const int j0 = jc0 + jt * BJ;

    __syncthreads();  // buf[cur] staged; prior reads of buf[cur^1] done

    // issue staging of NEXT tile into the other buffer (hidden under compute)
    if (jt < JCHUNK / BJ - 1) {
      const int jn = j0 + BJ;
#pragma unroll
      for (int q = 0; q < 4; ++q) {
        const int lrow = lrow0 + q * 8 + (lane >> 3);
        const int ch = (lane & 7) ^ (lrow & 7);
        const unsigned char* g = rq + (size_t)(jn + lrow) * ROWB + ch * 16;
        unsigned char* l = Bs[cur ^ 1] + (lrow0 + q * 8) * ROWB;
        __builtin_amdgcn_global_load_lds(
            (const __attribute__((address_space(1))) uint32_t*)g,
            (__attribute__((address_space(3))) uint32_t*)l, 16, 0, 0);
      }
    }

    int labj[8];
#pragma unroll
    for (int s = 0; s < 8; ++s) labj[s] = lab[j0 + s * 16 + l15];

    const unsigned char* Bb = Bs[cur];
#pragma unroll
    for (int s = 0; s < 8; ++s) {
      f32x4 acc0 = {0.f, 0.f, 0.f, 0.f};
      f32x4 acc1 = {0.f, 0.f, 0.f, 0.f};
      const int brow = s * 16 + l15;
      const unsigned char* bp = Bb + brow * ROWB;
      const int sw = brow & 7;
#pragma unroll
      for (int kc = 0; kc < 2; ++kc) {
        const int ch = (kc * 4 + lq) ^ sw;
        const u32x4 bv = *reinterpret_cast<const u32x4*>(bp + ch * 16);
        const i32x8 bb =
            (i32x8){(int)bv.x, (int)bv.y, (int)bv.z, (int)bv.w, 0, 0, 0, 0};
        // fmt codes: 4 = fp4 e2m1 for both A (cbsz) and B (blgp)
        acc0 = __builtin_amdgcn_mfma_scale_f32_16x16x128_f8f6f4(
            a[0][kc], bb, acc0, 4, 4, 0, SCALE_M3, 0, SCALE_M3);
        acc1 = __builtin_amdgcn_mfma_scale_f32_16x16x128_f8f6f4(
            a[1][kc], bb, acc1, 4, 4, 0, SCALE_M3, 0, SCALE_M3);
      }
#pragma unroll
      for (int r = 0; r < 4; ++r) {
        const float e0 = __builtin_amdgcn_exp2f(acc0[r]);
        const float e1 = __builtin_amdgcn_exp2f(acc1[r]);
        dsum[0][r] += (labi[0][r] == labj[s]) ? 1.0f : e0;
        dsum[1][r] += (labi[1][r] == labj[s]) ? 1.0f : e1;
      }
    }
  }

  // sum over the 16 lanes sharing each output row, then one atomic per row
#pragma unroll
  for (int t = 0; t < 2; ++t)
#pragma unroll
    for (int r = 0; r < 4; ++r) {
      float v = dsum[t][r];
      v += __shfl_xor(v, 1);
      v += __shfl_xor(v, 2);
      v += __shfl_xor(v, 4);
      v += __shfl_xor(v, 8);
      if (l15 == 0) atomicAdd(&den[ibase + t * 16 + lq * 4 + r], v);
    }
}

// ---- Kernel C: loss = mean(log(den + 1 + eps)) -----------------------------
__global__ void k_loss(const float* __restrict__ den, float* __restrict__ out) {
  const int idx = blockIdx.x * 256 + threadIdx.x;
  float v = logf(den[idx] + 1.0f + 1e-8f);  // +1 = num_diag
#pragma unroll
  for (int m = 1; m < 64; m <<= 1) v += __shfl_xor(v, m);
  __shared__ float sred[4];
  if ((threadIdx.x & 63) == 0) sred[threadIdx.x >> 6] = v;
  __syncthreads();
  if (threadIdx.x == 0)
    atomicAdd(out, (sred[0] + sred[1] + sred[2] + sred[3]) * (1.0f / (float)N_ROWS));
}

extern "C" void kernel_launch(void* const* d_in, const int* in_sizes, int n_in,
                              void* d_out, int out_size, void* d_ws, size_t ws_size,
                              hipStream_t stream) {
  const float* reps = (const float*)d_in[0];
  const int* lab = (const int*)d_in[1];
  float* out = (float*)d_out;
  unsigned char* rq = (unsigned char*)d_ws;                        // 1 MB fp4 q
  float* den = (float*)((char*)d_ws + (size_t)N_ROWS * ROWB);      // 32 KB

  k_norm<<<N_ROWS / 4, 256, 0, stream>>>(reps, rq, den, out);
  k_sim<<<dim3(N_ROWS / BM, JCHUNKS), 256, 0, stream>>>(rq, lab, den);
  k_loss<<<N_ROWS / 256, 256, 0, stream>>>(den, out);
}

// Round 17
// 29.573 us; speedup vs baseline: 1.7596x; 1.0238x over previous
//
#include <hip/hip_runtime.h>
#include <hip/hip_bf16.h>
#include <stdint.h>

typedef __attribute__((ext_vector_type(4))) float f32x4;
typedef __attribute__((ext_vector_type(4))) unsigned int u32x4;
typedef __attribute__((ext_vector_type(8))) int i32x8;

#define N_ROWS 8192
#define DIM 256            // K elements per row
#define ROWB 128           // bytes per row in fp4 (2 elems/byte)
#define BM 128             // i-rows per block (4 waves x 32 rows, t=2)
#define BJ 256             // j-cols staged per LDS super-tile (32 KB)
#define JCHUNKS 8
#define JCHUNK (N_ROWS / JCHUNKS)   // 1024 -> 4 super-tiles of 256 per block

// r' = r_normalized * sqrt(10*log2(e)); dot(r'_i,r'_j) = 10*log2(e)*sim,
// so exp(10*sim) = exp2(dot).
#define SCL 3.79828252f

// E8M0 scale 2^-3 in all 4 bytes (127-3=124): data quantized as q=8*r',
// scale applied to BOTH A and B -> products x 2^-6 = exact /64.
#define SCALE_M3 0x7C7C7C7C

// e2m1 RTNE quantizer: grid {0,.5,1,1.5,2,3,4,6} x sign
__device__ __forceinline__ uint32_t q_e2m1(float y) {
  const uint32_t s = (__builtin_bit_cast(uint32_t, y) >> 31) << 3;
  const float a = fabsf(y);
  const uint32_t c = (a < 0.25f) ? 0u : (a < 0.75f) ? 1u : (a < 1.25f) ? 2u
                   : (a < 1.75f) ? 3u : (a < 2.5f)  ? 4u : (a < 3.5f)  ? 5u
                   : (a < 5.0f)  ? 6u : 7u;
  return s | c;
}

// ---- Kernel A: normalize rows -> fp4 e2m1 q=8*r'; zero den & out -----------
__global__ void k_norm(const float* __restrict__ reps,
                       unsigned char* __restrict__ rq,
                       float* __restrict__ den,
                       float* __restrict__ out) {
  const int w = threadIdx.x >> 6, lane = threadIdx.x & 63;
  const int row = blockIdx.x * 4 + w;
  const float4 v = reinterpret_cast<const float4*>(reps + row * DIM)[lane];
  float ss = v.x * v.x + v.y * v.y + v.z * v.z + v.w * v.w;
#pragma unroll
  for (int m = 1; m < 64; m <<= 1) ss += __shfl_xor(ss, m);
  const float qs = 8.0f * SCL / fmaxf(sqrtf(ss), 1e-12f);
  const uint32_t nib = q_e2m1(v.x * qs) | (q_e2m1(v.y * qs) << 4) |
                       (q_e2m1(v.z * qs) << 8) | (q_e2m1(v.w * qs) << 12);
  *reinterpret_cast<unsigned short*>(rq + (size_t)row * ROWB + lane * 2) =
      (unsigned short)nib;
  if (threadIdx.x < 4) den[blockIdx.x * 4 + threadIdx.x] = 0.0f;
  if (blockIdx.x == 0 && threadIdx.x == 0) out[0] = 0.0f;
}

// ---- Kernel B: MX-fp4 (16x16x128) fused sim + exp + mask + row-sum ---------
// R15's verified structure (grid (64,8), 256 thr, dbuf LDS, 1 barrier/tile,
// prefetch into other buffer) with BJ=256 super-tiles: fp4 tiles are 16 KB,
// two fit per 32 KB buffer -> half the barrier/vmcnt-drain periods, each
// compute phase 2x longer to hide the next stage. (R16's cooperative-launch
// fusion silently no-ops under graph capture — reverted; this is the
// surviving half of that round.)
__global__ __launch_bounds__(256, 2) void k_sim(
    const unsigned char* __restrict__ rq,
    const int* __restrict__ lab,
    float* __restrict__ den) {
  __shared__ unsigned char Bs[2][BJ * ROWB];  // 2 x 32 KB, 16B-chunk XOR-swizzled

  const int tid = threadIdx.x;
  const int w = tid >> 6, lane = tid & 63;
  const int l15 = lane & 15, lq = lane >> 4;
  const int ibase = blockIdx.x * BM + w * 32;   // this wave's 32 rows
  const int jc0 = blockIdx.y * JCHUNK;

  // A fragments: 2 i-subtiles x 2 K-windows; fp4 uses 16B/lane (4 VGPR) in
  // regs 0-3 of the v8i32 operand. Window kc = row bytes [kc*64+lq*16,+16).
  // Same map for A and B from the same matrix -> any k-permutation cancels.
  i32x8 a[2][2];
#pragma unroll
  for (int t = 0; t < 2; ++t) {
    const unsigned char* ap = rq + (size_t)(ibase + t * 16 + l15) * ROWB;
#pragma unroll
    for (int kc = 0; kc < 2; ++kc) {
      const u32x4 v0 = *reinterpret_cast<const u32x4*>(ap + kc * 64 + lq * 16);
      a[t][kc] = (i32x8){(int)v0.x, (int)v0.y, (int)v0.z, (int)v0.w, 0, 0, 0, 0};
    }
  }
  int labi[2][4];
#pragma unroll
  for (int t = 0; t < 2; ++t)
#pragma unroll
    for (int r = 0; r < 4; ++r)
      labi[t][r] = lab[ibase + t * 16 + lq * 4 + r];

  f32x4 dsum[2] = {{0.f, 0.f, 0.f, 0.f}, {0.f, 0.f, 0.f, 0.f}};

  const int lrow0 = w * 64;  // each wave stages 64 rows (8 instr x 8 rows)

  // prologue: stage super-tile 0 into buf 0 (32 KB: 8 instr x 4 waves x 1 KB)
#pragma unroll
  for (int q = 0; q < 8; ++q) {
    const int lrow = lrow0 + q * 8 + (lane >> 3);
    const int ch = (lane & 7) ^ (lrow & 7);  // 16B-chunk swizzle (8 chunks/row)
    const unsigned char* g = rq + (size_t)(jc0 + lrow) * ROWB + ch * 16;
    unsigned char* l = Bs[0] + (lrow0 + q * 8) * ROWB;  // +lane*16 implicit
    __builtin_amdgcn_global_load_lds(
        (const __attribute__((address_space(1))) uint32_t*)g,
        (__attribute__((address_space(3))) uint32_t*)l, 16, 0, 0);
  }

  for (int jt = 0; jt < JCHUNK / BJ; ++jt) {
    const int cur = jt & 1;
    const int j0 = jc0 + jt * BJ;

    __syncthreads();  // buf[cur] staged; prior reads of buf[cur^1] done

    // issue staging of NEXT super-tile into the other buffer
    if (jt < JCHUNK / BJ - 1) {
      const int jn = j0 + BJ;
#pragma unroll
      for (int q = 0; q < 8; ++q) {
        const int lrow = lrow0 + q * 8 + (lane >> 3);
        const int ch = (lane & 7) ^ (lrow & 7);
        const unsigned char* g = rq + (size_t)(jn + lrow) * ROWB + ch * 16;
        unsigned char* l = Bs[cur ^ 1] + (lrow0 + q * 8) * ROWB;
        __builtin_amdgcn_global_load_lds(
            (const __attribute__((address_space(1))) uint32_t*)g,
            (__attribute__((address_space(3))) uint32_t*)l, 16, 0, 0);
      }
    }

    int labj[16];
#pragma unroll
    for (int s = 0; s < 16; ++s) labj[s] = lab[j0 + s * 16 + l15];

    const unsigned char* Bb = Bs[cur];
#pragma unroll
    for (int s = 0; s < 16; ++s) {
      f32x4 acc0 = {0.f, 0.f, 0.f, 0.f};
      f32x4 acc1 = {0.f, 0.f, 0.f, 0.f};
      const int brow = s * 16 + l15;
      const unsigned char* bp = Bb + brow * ROWB;
      const int sw = brow & 7;
#pragma unroll
      for (int kc = 0; kc < 2; ++kc) {
        const int ch = (kc * 4 + lq) ^ sw;
        const u32x4 bv = *reinterpret_cast<const u32x4*>(bp + ch * 16);
        const i32x8 bb =
            (i32x8){(int)bv.x, (int)bv.y, (int)bv.z, (int)bv.w, 0, 0, 0, 0};
        // fmt codes: 4 = fp4 e2m1 for both A (cbsz) and B (blgp)
        acc0 = __builtin_amdgcn_mfma_scale_f32_16x16x128_f8f6f4(
            a[0][kc], bb, acc0, 4, 4, 0, SCALE_M3, 0, SCALE_M3);
        acc1 = __builtin_amdgcn_mfma_scale_f32_16x16x128_f8f6f4(
            a[1][kc], bb, acc1, 4, 4, 0, SCALE_M3, 0, SCALE_M3);
      }
#pragma unroll
      for (int r = 0; r < 4; ++r) {
        const float e0 = __builtin_amdgcn_exp2f(acc0[r]);
        const float e1 = __builtin_amdgcn_exp2f(acc1[r]);
        dsum[0][r] += (labi[0][r] == labj[s]) ? 1.0f : e0;
        dsum[1][r] += (labi[1][r] == labj[s]) ? 1.0f : e1;
      }
    }
  }

  // sum over the 16 lanes sharing each output row, then one atomic per row
#pragma unroll
  for (int t = 0; t < 2; ++t)
#pragma unroll
    for (int r = 0; r < 4; ++r) {
      float v = dsum[t][r];
      v += __shfl_xor(v, 1);
      v += __shfl_xor(v, 2);
      v += __shfl_xor(v, 4);
      v += __shfl_xor(v, 8);
      if (l15 == 0) atomicAdd(&den[ibase + t * 16 + lq * 4 + r], v);
    }
}

// ---- Kernel C: loss = mean(log(den + 1 + eps)) -----------------------------
__global__ void k_loss(const float* __restrict__ den, float* __restrict__ out) {
  const int idx = blockIdx.x * 256 + threadIdx.x;
  float v = logf(den[idx] + 1.0f + 1e-8f);  // +1 = num_diag
#pragma unroll
  for (int m = 1; m < 64; m <<= 1) v += __shfl_xor(v, m);
  __shared__ float sred[4];
  if ((threadIdx.x & 63) == 0) sred[threadIdx.x >> 6] = v;
  __syncthreads();
  if (threadIdx.x == 0)
    atomicAdd(out, (sred[0] + sred[1] + sred[2] + sred[3]) * (1.0f / (float)N_ROWS));
}

extern "C" void kernel_launch(void* const* d_in, const int* in_sizes, int n_in,
                              void* d_out, int out_size, void* d_ws, size_t ws_size,
                              hipStream_t stream) {
  const float* reps = (const float*)d_in[0];
  const int* lab = (const int*)d_in[1];
  float* out = (float*)d_out;
  unsigned char* rq = (unsigned char*)d_ws;                        // 1 MB fp4 q
  float* den = (float*)((char*)d_ws + (size_t)N_ROWS * ROWB);      // 32 KB

  k_norm<<<N_ROWS / 4, 256, 0, stream>>>(reps, rq, den, out);
  k_sim<<<dim3(N_ROWS / BM, JCHUNKS), 256, 0, stream>>>(rq, lab, den);
  k_loss<<<N_ROWS / 256, 256, 0, stream>>>(den, out);
}